// Round 1
// baseline (2345.641 us; speedup 1.0000x reference)
//
#include <hip/hip_runtime.h>
#include <math.h>

#define FEAT 128
#define NRBF 20
#define NCONV 3
#define PI_F 3.14159265358979323846f

// ---------------------------------------------------------------------------
// Generic fp32 GEMM: C[M,N] = A[M,K] @ W[N,K]^T + bias[N], optional silu.
// 64x64 tile, BK=16, 256 threads, 4x4 microtile.
// ---------------------------------------------------------------------------
#define BM 64
#define BN 64
#define BKT 16

__global__ __launch_bounds__(256) void gemm_bias_kernel(
    const float* __restrict__ A, const float* __restrict__ W,
    const float* __restrict__ bias, float* __restrict__ C,
    int M, int N, int K, int act)
{
    __shared__ float As[BKT][BM + 1];
    __shared__ float Bs[BKT][BN + 1];
    const int m0 = blockIdx.x * BM;
    const int n0 = blockIdx.y * BN;
    const int t  = threadIdx.x;
    const int tx = t & 15;   // n direction
    const int ty = t >> 4;   // m direction
    float acc[4][4] = {{0.f}};

    for (int k0 = 0; k0 < K; k0 += BKT) {
        #pragma unroll
        for (int i = 0; i < 4; ++i) {
            int e = t + i * 256;          // 0..1023 over 64 rows x 16 cols
            int r = e >> 4, c = e & 15;
            int m = m0 + r;
            As[c][r] = (m < M) ? A[(long)m * K + k0 + c] : 0.f;
            Bs[c][r] = W[(long)(n0 + r) * K + k0 + c];   // N % 64 == 0 always
        }
        __syncthreads();
        #pragma unroll
        for (int k = 0; k < BKT; ++k) {
            float a[4], b[4];
            #pragma unroll
            for (int i = 0; i < 4; ++i) a[i] = As[k][ty * 4 + i];
            #pragma unroll
            for (int j = 0; j < 4; ++j) b[j] = Bs[k][tx * 4 + j];
            #pragma unroll
            for (int i = 0; i < 4; ++i)
                #pragma unroll
                for (int j = 0; j < 4; ++j)
                    acc[i][j] += a[i] * b[j];
        }
        __syncthreads();
    }

    #pragma unroll
    for (int i = 0; i < 4; ++i) {
        int m = m0 + ty * 4 + i;
        if (m >= M) continue;
        #pragma unroll
        for (int j = 0; j < 4; ++j) {
            int n = n0 + tx * 4 + j;
            float x = acc[i][j] + (bias ? bias[n] : 0.f);
            if (act) x = x / (1.f + __expf(-x));   // silu
            C[(long)m * N + n] = x;
        }
    }
}

// ---------------------------------------------------------------------------
// Edge geometry (layer-invariant): unit vector, envelope, env*rbf
// ---------------------------------------------------------------------------
__global__ __launch_bounds__(256) void edge_geom_kernel(
    const int* __restrict__ nbr, const float* __restrict__ xyz,
    float* __restrict__ unitv, float* __restrict__ env,
    float* __restrict__ rbfe, int Ed)
{
    int e = blockIdx.x * blockDim.x + threadIdx.x;
    if (e >= Ed) return;
    int i, j;
    int E = Ed >> 1;
    if (e < E) { i = nbr[2 * e];         j = nbr[2 * e + 1]; }
    else       { int u = e - E; i = nbr[2 * u + 1]; j = nbr[2 * u]; }
    float rx = xyz[3 * j + 0] - xyz[3 * i + 0];
    float ry = xyz[3 * j + 1] - xyz[3 * i + 1];
    float rz = xyz[3 * j + 2] - xyz[3 * i + 2];
    float d   = sqrtf(rx * rx + ry * ry + rz * rz);
    float inv = 1.f / d;
    unitv[3 * e + 0] = rx * inv;
    unitv[3 * e + 1] = ry * inv;
    unitv[3 * e + 2] = rz * inv;
    float ev = (d < 20.f) ? 0.5f * (__cosf(PI_F * d / 20.f) + 1.f) : 0.f;
    env[e] = ev;
    float base = PI_F * d / 20.f;
    #pragma unroll
    for (int k = 0; k < NRBF; ++k)
        rbfe[(long)e * NRBF + k] = ev * __sinf((float)(k + 1) * base) * inv;
}

// ---------------------------------------------------------------------------
// Fused edge-message kernel: w_s from LDS-staged dist_W, gather phi[j]/v[j],
// scatter-add (atomics) into s and vnew.  256 threads = 2 edges x 128 feats.
// ---------------------------------------------------------------------------
#define EPB 32

__global__ __launch_bounds__(256) void edge_msg_kernel(
    const int* __restrict__ nbr, const float* __restrict__ rbfe,
    const float* __restrict__ env, const float* __restrict__ unitv,
    const float* __restrict__ phi, const float* __restrict__ vold,
    const float* __restrict__ distW, const float* __restrict__ distb,
    float* __restrict__ s, float* __restrict__ vnew, int Ed, int SP)
{
    __shared__ float Wl[384 * 21];   // stride 21: coprime with 32 banks
    __shared__ float bl[384];
    const int t = threadIdx.x;
    for (int idx = t; idx < 384 * NRBF; idx += 256) {
        int c = idx / NRBF, k = idx % NRBF;
        Wl[c * 21 + k] = distW[idx];
    }
    for (int idx = t; idx < 384; idx += 256) bl[idx] = distb[idx];
    __syncthreads();

    const int sub = t >> 7;     // 0..1 (edge within pair)
    const int f   = t & 127;    // feature
    const int e0  = blockIdx.x * EPB;
    const int E   = Ed >> 1;

    for (int it = 0; it < EPB; it += 2) {
        int e = e0 + it + sub;
        if (e >= Ed) break;
        int i, j;
        if (e < E) { i = nbr[2 * e];         j = nbr[2 * e + 1]; }
        else       { int u = e - E; i = nbr[2 * u + 1]; j = nbr[2 * u]; }

        float ev = env[e];
        float w0 = ev * bl[f];
        float w1 = ev * bl[128 + f];
        float w2 = ev * bl[256 + f];
        const float* rb = rbfe + (long)e * NRBF;
        #pragma unroll
        for (int k = 0; k < NRBF; ++k) {
            float r = rb[k];
            w0 += r * Wl[f * 21 + k];
            w1 += r * Wl[(128 + f) * 21 + k];
            w2 += r * Wl[(256 + f) * 21 + k];
        }
        long jb = (long)j * 384;
        float inv0 = phi[jb + f]       * w0;
        float inv1 = phi[jb + 128 + f] * w1;
        float inv2 = phi[jb + 256 + f] * w2;

        atomicAdd(&s[(long)i * FEAT + f], inv1);

        float ux = unitv[3 * e + 0], uy = unitv[3 * e + 1], uz = unitv[3 * e + 2];
        long jv = (long)j * FEAT + f;
        long iv = (long)i * FEAT + f;
        atomicAdd(&vnew[iv],            inv2 * ux + inv0 * vold[jv]);
        atomicAdd(&vnew[SP + iv],       inv2 * uy + inv0 * vold[SP + jv]);
        atomicAdd(&vnew[2 * SP + iv],   inv2 * uz + inv0 * vold[2 * SP + jv]);
    }
}

// ---------------------------------------------------------------------------
// Elementwise kernels
// ---------------------------------------------------------------------------
__global__ __launch_bounds__(256) void init_sv_kernel(
    const float* __restrict__ cg_s, float* __restrict__ s,
    float* __restrict__ vA, int nS, int nV)
{
    int idx = blockIdx.x * blockDim.x + threadIdx.x;
    if (idx < nS) s[idx] = cg_s[idx];
    if (idx < nV) vA[idx] = 0.f;
}

__global__ __launch_bounds__(256) void cat_norm_kernel(
    const float* __restrict__ s, const float* __restrict__ vv,
    float* __restrict__ cat, int SP)
{
    int idx = blockIdx.x * blockDim.x + threadIdx.x;
    if (idx >= SP) return;
    int n = idx >> 7, g = idx & 127;
    float a0 = vv[idx], a1 = vv[SP + idx], a2 = vv[2 * SP + idx];
    cat[(long)n * 256 + g]       = s[idx];
    cat[(long)n * 256 + 128 + g] = sqrtf(a0 * a0 + a1 * a1 + a2 * a2);
}

__global__ __launch_bounds__(256) void update_sv_kernel(
    float* __restrict__ s, float* __restrict__ v,
    const float* __restrict__ uv, const float* __restrict__ vv,
    const float* __restrict__ a, int SP)
{
    int idx = blockIdx.x * blockDim.x + threadIdx.x;
    if (idx >= SP) return;
    int n = idx >> 7, g = idx & 127;
    float u0 = uv[idx], u1 = uv[SP + idx], u2 = uv[2 * SP + idx];
    float w0 = vv[idx], w1 = vv[SP + idx], w2 = vv[2 * SP + idx];
    long ab = (long)n * 384;
    float dot = u0 * w0 + u1 * w1 + u2 * w2;
    s[idx] += dot * a[ab + 128 + g] + a[ab + 256 + g];
    float g0 = a[ab + g];
    v[idx]          += u0 * g0;
    v[SP + idx]     += u1 * g0;
    v[2 * SP + idx] += u2 * g0;
}

__global__ __launch_bounds__(256) void write_out_kernel(
    const float* __restrict__ vfin, float* __restrict__ outv, int SP)
{
    int idx = blockIdx.x * blockDim.x + threadIdx.x;
    if (idx >= SP) return;
    outv[(long)idx * 3 + 0] = vfin[idx];
    outv[(long)idx * 3 + 1] = vfin[SP + idx];
    outv[(long)idx * 3 + 2] = vfin[2 * SP + idx];
}

// ---------------------------------------------------------------------------
extern "C" void kernel_launch(void* const* d_in, const int* in_sizes, int n_in,
                              void* d_out, int out_size, void* d_ws, size_t ws_size,
                              hipStream_t stream)
{
    const float* xyz     = (const float*)d_in[0];
    const int*   nbr     = (const int*)  d_in[1];
    const float* cg_s    = (const float*)d_in[2];
    const float* msg_W1  = (const float*)d_in[3];
    const float* msg_b1  = (const float*)d_in[4];
    const float* msg_W2  = (const float*)d_in[5];
    const float* msg_b2  = (const float*)d_in[6];
    const float* dist_W  = (const float*)d_in[7];
    const float* dist_b  = (const float*)d_in[8];
    const float* upd_U   = (const float*)d_in[9];
    const float* upd_V   = (const float*)d_in[10];
    const float* upd_sW1 = (const float*)d_in[11];
    const float* upd_sb1 = (const float*)d_in[12];
    const float* upd_sW2 = (const float*)d_in[13];
    const float* upd_sb2 = (const float*)d_in[14];

    const int E  = in_sizes[1] / 2;
    const int Ed = 2 * E;
    const int N  = in_sizes[2] / FEAT;
    const int SP = N * FEAT;                  // one v plane

    float* s    = (float*)d_out;              // (N,128) lives in output
    float* outv = (float*)d_out + (long)SP;   // final (N,128,3) region
    float* u_v  = outv;                       // alias: u_v planes (dead by output time)

    // workspace carve-up (fp32 elements, 256-aligned)
    float* w = (float*)d_ws;
    size_t off = 0;
    auto alloc = [&](size_t nelem) {
        float* p = w + off;
        off += (nelem + 255) & ~(size_t)255;
        return p;
    };
    float* unitv = alloc((size_t)Ed * 3);
    float* env   = alloc((size_t)Ed);
    float* rbfe  = alloc((size_t)Ed * NRBF);
    float* h     = alloc((size_t)SP);          // hidden (N,128)
    float* cat   = alloc((size_t)N * 256);     // [s | ||v_v||]
    float* phi   = alloc((size_t)N * 384);     // phi, reused for 'a'
    float* vA    = alloc((size_t)3 * SP);
    float* vB    = alloc((size_t)3 * SP);
    float* v_v   = alloc((size_t)3 * SP);
    (void)ws_size; (void)n_in; (void)out_size;

    // init s <- cg_s, vA <- 0
    {
        int n = 3 * SP;
        init_sv_kernel<<<(n + 255) / 256, 256, 0, stream>>>(cg_s, s, vA, SP, n);
    }
    edge_geom_kernel<<<(Ed + 255) / 256, 256, 0, stream>>>(nbr, xyz, unitv, env, rbfe, Ed);

    float* vold = vA;
    float* vnew = vB;
    dim3 g1((N + BM - 1) / BM, FEAT / BN);       // N-cols = 128
    dim3 g2((N + BM - 1) / BM, (3 * FEAT) / BN); // N-cols = 384

    for (int l = 0; l < NCONV; ++l) {
        const float* W1  = msg_W1  + (long)l * FEAT * FEAT;
        const float* b1  = msg_b1  + (long)l * FEAT;
        const float* W2  = msg_W2  + (long)l * 3 * FEAT * FEAT;
        const float* b2  = msg_b2  + (long)l * 3 * FEAT;
        const float* dW  = dist_W  + (long)l * 3 * FEAT * NRBF;
        const float* db  = dist_b  + (long)l * 3 * FEAT;
        const float* U   = upd_U   + (long)l * FEAT * FEAT;
        const float* V   = upd_V   + (long)l * FEAT * FEAT;
        const float* sW1 = upd_sW1 + (long)l * FEAT * 2 * FEAT;
        const float* sb1 = upd_sb1 + (long)l * FEAT;
        const float* sW2 = upd_sW2 + (long)l * 3 * FEAT * FEAT;
        const float* sb2 = upd_sb2 + (long)l * 3 * FEAT;

        // phi-MLP
        gemm_bias_kernel<<<g1, 256, 0, stream>>>(s, W1, b1, h, N, FEAT, FEAT, 1);
        gemm_bias_kernel<<<g2, 256, 0, stream>>>(h, W2, b2, phi, N, 3 * FEAT, FEAT, 0);

        // message passing: vnew = vold + sum; s += sum
        hipMemcpyAsync(vnew, vold, (size_t)3 * SP * sizeof(float),
                       hipMemcpyDeviceToDevice, stream);
        edge_msg_kernel<<<(Ed + EPB - 1) / EPB, 256, 0, stream>>>(
            nbr, rbfe, env, unitv, phi, vold, dW, db, s, vnew, Ed, SP);

        // u_v / v_v per plane
        for (int d = 0; d < 3; ++d) {
            gemm_bias_kernel<<<g1, 256, 0, stream>>>(
                vnew + (long)d * SP, U, nullptr, u_v + (long)d * SP, N, FEAT, FEAT, 0);
            gemm_bias_kernel<<<g1, 256, 0, stream>>>(
                vnew + (long)d * SP, V, nullptr, v_v + (long)d * SP, N, FEAT, FEAT, 0);
        }

        // gate MLP
        cat_norm_kernel<<<(SP + 255) / 256, 256, 0, stream>>>(s, v_v, cat, SP);
        gemm_bias_kernel<<<g1, 256, 0, stream>>>(cat, sW1, sb1, h, N, FEAT, 2 * FEAT, 1);
        gemm_bias_kernel<<<g2, 256, 0, stream>>>(h, sW2, sb2, phi, N, 3 * FEAT, FEAT, 0);

        // final update (phi buffer now holds 'a')
        update_sv_kernel<<<(SP + 255) / 256, 256, 0, stream>>>(s, vnew, u_v, v_v, phi, SP);

        float* tmp = vold; vold = vnew; vnew = tmp;
    }

    // vold holds final v; s already in place at d_out[0:SP]
    write_out_kernel<<<(SP + 255) / 256, 256, 0, stream>>>(vold, outv, SP);
}

// Round 2
// 1686.940 us; speedup vs baseline: 1.3905x; 1.3905x over previous
//
#include <hip/hip_runtime.h>
#include <math.h>

#define FEAT 128
#define NRBF 20
#define NCONV 3
#define PI_F 3.14159265358979323846f

// ---------------------------------------------------------------------------
// Generic fp32 GEMM: C[M,N] = A[M,K] @ W[N,K]^T + bias[N], optional silu.
// 64x64 tile, BK=16, 256 threads, 4x4 microtile.  (unchanged from R0)
// ---------------------------------------------------------------------------
#define BM 64
#define BN 64
#define BKT 16

__global__ __launch_bounds__(256) void gemm_bias_kernel(
    const float* __restrict__ A, const float* __restrict__ W,
    const float* __restrict__ bias, float* __restrict__ C,
    int M, int N, int K, int act)
{
    __shared__ float As[BKT][BM + 1];
    __shared__ float Bs[BKT][BN + 1];
    const int m0 = blockIdx.x * BM;
    const int n0 = blockIdx.y * BN;
    const int t  = threadIdx.x;
    const int tx = t & 15;   // n direction
    const int ty = t >> 4;   // m direction
    float acc[4][4] = {{0.f}};

    for (int k0 = 0; k0 < K; k0 += BKT) {
        #pragma unroll
        for (int i = 0; i < 4; ++i) {
            int e = t + i * 256;
            int r = e >> 4, c = e & 15;
            int m = m0 + r;
            As[c][r] = (m < M) ? A[(long)m * K + k0 + c] : 0.f;
            Bs[c][r] = W[(long)(n0 + r) * K + k0 + c];
        }
        __syncthreads();
        #pragma unroll
        for (int k = 0; k < BKT; ++k) {
            float a[4], b[4];
            #pragma unroll
            for (int i = 0; i < 4; ++i) a[i] = As[k][ty * 4 + i];
            #pragma unroll
            for (int j = 0; j < 4; ++j) b[j] = Bs[k][tx * 4 + j];
            #pragma unroll
            for (int i = 0; i < 4; ++i)
                #pragma unroll
                for (int j = 0; j < 4; ++j)
                    acc[i][j] += a[i] * b[j];
        }
        __syncthreads();
    }

    #pragma unroll
    for (int i = 0; i < 4; ++i) {
        int m = m0 + ty * 4 + i;
        if (m >= M) continue;
        #pragma unroll
        for (int j = 0; j < 4; ++j) {
            int n = n0 + tx * 4 + j;
            float x = acc[i][j] + (bias ? bias[n] : 0.f);
            if (act) x = x / (1.f + __expf(-x));   // silu
            C[(long)m * N + n] = x;
        }
    }
}

// ---------------------------------------------------------------------------
// CSR build: histogram of destination node i over 2E directed edges
// ---------------------------------------------------------------------------
__global__ __launch_bounds__(256) void hist_kernel(
    const int* __restrict__ nbr, int* __restrict__ deg, int Ed)
{
    int e = blockIdx.x * blockDim.x + threadIdx.x;
    if (e >= Ed) return;
    int E = Ed >> 1;
    int i = (e < E) ? nbr[2 * e] : nbr[2 * (e - E) + 1];
    atomicAdd(&deg[i], 1);
}

// single-block scan: off[0]=0, off[i+1]=incl_sum(deg[0..i]), cursor[i]=off[i]
__device__ inline int wave_incl_scan(int x, int lane)
{
    #pragma unroll
    for (int s = 1; s < 64; s <<= 1) {
        int y = __shfl_up(x, s, 64);
        if (lane >= s) x += y;
    }
    return x;
}

__global__ __launch_bounds__(1024) void scan_kernel(
    const int* __restrict__ deg, int* __restrict__ off,
    int* __restrict__ cursor, int N)
{
    __shared__ int wsum[16];
    __shared__ int carry_s;
    const int t = threadIdx.x;
    const int lane = t & 63;
    const int w = t >> 6;
    if (t == 0) { carry_s = 0; off[0] = 0; }
    __syncthreads();
    for (int base = 0; base < N; base += 1024) {
        int i = base + t;
        int x = (i < N) ? deg[i] : 0;
        int sc = wave_incl_scan(x, lane);
        if (lane == 63) wsum[w] = sc;
        __syncthreads();
        if (w == 0) {
            int v = (lane < 16) ? wsum[lane] : 0;
            int vs = wave_incl_scan(v, lane);
            if (lane < 16) wsum[lane] = vs;
        }
        __syncthreads();
        int waveoff = (w > 0) ? wsum[w - 1] : 0;
        int inc = sc + waveoff + carry_s;
        if (i < N) { off[i + 1] = inc; cursor[i] = inc - x; }
        __syncthreads();
        if (t == 1023) carry_s = inc;
        __syncthreads();
    }
}

// ---------------------------------------------------------------------------
// Scatter + edge geometry directly into CSR order (one-time, layer-invariant)
// ---------------------------------------------------------------------------
__global__ __launch_bounds__(256) void scatter_geom_kernel(
    const int* __restrict__ nbr, const float* __restrict__ xyz,
    int* __restrict__ cursor, int* __restrict__ csr_j,
    float* __restrict__ csr_env, float* __restrict__ csr_unit,
    float* __restrict__ csr_rbfe, int Ed)
{
    int e = blockIdx.x * blockDim.x + threadIdx.x;
    if (e >= Ed) return;
    int E = Ed >> 1;
    int i, j;
    if (e < E) { i = nbr[2 * e];         j = nbr[2 * e + 1]; }
    else       { int u = e - E; i = nbr[2 * u + 1]; j = nbr[2 * u]; }

    int p = atomicAdd(&cursor[i], 1);
    csr_j[p] = j;

    float rx = xyz[3 * j + 0] - xyz[3 * i + 0];
    float ry = xyz[3 * j + 1] - xyz[3 * i + 1];
    float rz = xyz[3 * j + 2] - xyz[3 * i + 2];
    float d   = sqrtf(rx * rx + ry * ry + rz * rz);
    float inv = 1.f / d;
    csr_unit[3 * p + 0] = rx * inv;
    csr_unit[3 * p + 1] = ry * inv;
    csr_unit[3 * p + 2] = rz * inv;
    float ev = (d < 20.f) ? 0.5f * (__cosf(PI_F * d / 20.f) + 1.f) : 0.f;
    csr_env[p] = ev;
    float base = PI_F * d / 20.f;
    #pragma unroll
    for (int k = 0; k < NRBF; ++k)
        csr_rbfe[(long)p * NRBF + k] = ev * __sinf((float)(k + 1) * base) * inv;
}

// ---------------------------------------------------------------------------
// Edge aggregation, atomic-free: one 128-thread block slice per node,
// dist_W weights register-resident (63 VGPR/thread), per-edge scalars are
// wave-uniform (scalar loads).  Writes s += sum and vnew = vold + sum.
// ---------------------------------------------------------------------------
__global__ __launch_bounds__(128) void edge_aggr_kernel(
    const int* __restrict__ off, const int* __restrict__ csr_j,
    const float* __restrict__ csr_env, const float* __restrict__ csr_unit,
    const float* __restrict__ csr_rbfe,
    const float* __restrict__ phi, const float* __restrict__ vold,
    const float* __restrict__ distW, const float* __restrict__ distb,
    float* __restrict__ s, float* __restrict__ vnew, int N, int SP)
{
    const int f = threadIdx.x;          // feature 0..127
    float w0c[NRBF], w1c[NRBF], w2c[NRBF];
    const float b0 = distb[f];
    const float b1 = distb[128 + f];
    const float b2 = distb[256 + f];
    #pragma unroll
    for (int k = 0; k < NRBF; ++k) {
        w0c[k] = distW[(long)f * NRBF + k];
        w1c[k] = distW[(long)(128 + f) * NRBF + k];
        w2c[k] = distW[(long)(256 + f) * NRBF + k];
    }

    for (int node = blockIdx.x; node < N; node += gridDim.x) {
        const int p0 = off[node], p1 = off[node + 1];
        float ssum = 0.f, v0 = 0.f, v1 = 0.f, v2 = 0.f;
        for (int p = p0; p < p1; ++p) {
            int j = csr_j[p];
            float ev = csr_env[p];
            float ux = csr_unit[3 * p + 0];
            float uy = csr_unit[3 * p + 1];
            float uz = csr_unit[3 * p + 2];
            const float* rb = csr_rbfe + (long)p * NRBF;
            float w0 = ev * b0, w1 = ev * b1, w2 = ev * b2;
            #pragma unroll
            for (int k = 0; k < NRBF; ++k) {
                float r = rb[k];
                w0 += r * w0c[k];
                w1 += r * w1c[k];
                w2 += r * w2c[k];
            }
            long jb = (long)j * 384;
            float i0 = phi[jb + f]       * w0;
            float i1 = phi[jb + 128 + f] * w1;
            float i2 = phi[jb + 256 + f] * w2;
            long jv = (long)j * FEAT + f;
            ssum += i1;
            v0 += i2 * ux + i0 * vold[jv];
            v1 += i2 * uy + i0 * vold[SP + jv];
            v2 += i2 * uz + i0 * vold[2 * SP + jv];
        }
        long iv = (long)node * FEAT + f;
        s[iv] += ssum;
        vnew[iv]          = vold[iv]          + v0;
        vnew[SP + iv]     = vold[SP + iv]     + v1;
        vnew[2 * SP + iv] = vold[2 * SP + iv] + v2;
    }
}

// ---------------------------------------------------------------------------
// Elementwise kernels (unchanged)
// ---------------------------------------------------------------------------
__global__ __launch_bounds__(256) void init_s_kernel(
    const float* __restrict__ cg_s, float* __restrict__ s,
    float* __restrict__ vA, int nS, int nV)
{
    int idx = blockIdx.x * blockDim.x + threadIdx.x;
    if (idx < nS) s[idx] = cg_s[idx];
    if (idx < nV) vA[idx] = 0.f;
}

__global__ __launch_bounds__(256) void cat_norm_kernel(
    const float* __restrict__ s, const float* __restrict__ vv,
    float* __restrict__ cat, int SP)
{
    int idx = blockIdx.x * blockDim.x + threadIdx.x;
    if (idx >= SP) return;
    int n = idx >> 7, g = idx & 127;
    float a0 = vv[idx], a1 = vv[SP + idx], a2 = vv[2 * SP + idx];
    cat[(long)n * 256 + g]       = s[idx];
    cat[(long)n * 256 + 128 + g] = sqrtf(a0 * a0 + a1 * a1 + a2 * a2);
}

__global__ __launch_bounds__(256) void update_sv_kernel(
    float* __restrict__ s, float* __restrict__ v,
    const float* __restrict__ uv, const float* __restrict__ vv,
    const float* __restrict__ a, int SP)
{
    int idx = blockIdx.x * blockDim.x + threadIdx.x;
    if (idx >= SP) return;
    int n = idx >> 7, g = idx & 127;
    float u0 = uv[idx], u1 = uv[SP + idx], u2 = uv[2 * SP + idx];
    float w0 = vv[idx], w1 = vv[SP + idx], w2 = vv[2 * SP + idx];
    long ab = (long)n * 384;
    float dot = u0 * w0 + u1 * w1 + u2 * w2;
    s[idx] += dot * a[ab + 128 + g] + a[ab + 256 + g];
    float g0 = a[ab + g];
    v[idx]          += u0 * g0;
    v[SP + idx]     += u1 * g0;
    v[2 * SP + idx] += u2 * g0;
}

__global__ __launch_bounds__(256) void write_out_kernel(
    const float* __restrict__ vfin, float* __restrict__ outv, int SP)
{
    int idx = blockIdx.x * blockDim.x + threadIdx.x;
    if (idx >= SP) return;
    outv[(long)idx * 3 + 0] = vfin[idx];
    outv[(long)idx * 3 + 1] = vfin[SP + idx];
    outv[(long)idx * 3 + 2] = vfin[2 * SP + idx];
}

// ---------------------------------------------------------------------------
extern "C" void kernel_launch(void* const* d_in, const int* in_sizes, int n_in,
                              void* d_out, int out_size, void* d_ws, size_t ws_size,
                              hipStream_t stream)
{
    const float* xyz     = (const float*)d_in[0];
    const int*   nbr     = (const int*)  d_in[1];
    const float* cg_s    = (const float*)d_in[2];
    const float* msg_W1  = (const float*)d_in[3];
    const float* msg_b1  = (const float*)d_in[4];
    const float* msg_W2  = (const float*)d_in[5];
    const float* msg_b2  = (const float*)d_in[6];
    const float* dist_W  = (const float*)d_in[7];
    const float* dist_b  = (const float*)d_in[8];
    const float* upd_U   = (const float*)d_in[9];
    const float* upd_V   = (const float*)d_in[10];
    const float* upd_sW1 = (const float*)d_in[11];
    const float* upd_sb1 = (const float*)d_in[12];
    const float* upd_sW2 = (const float*)d_in[13];
    const float* upd_sb2 = (const float*)d_in[14];

    const int E  = in_sizes[1] / 2;
    const int Ed = 2 * E;
    const int N  = in_sizes[2] / FEAT;
    const int SP = N * FEAT;

    float* s    = (float*)d_out;
    float* outv = (float*)d_out + (long)SP;
    float* u_v  = outv;   // alias: u_v planes dead by output time

    // workspace carve-up
    float* w = (float*)d_ws;
    size_t off_ = 0;
    auto alloc = [&](size_t nelem) {
        float* p = w + off_;
        off_ += (nelem + 255) & ~(size_t)255;
        return p;
    };
    int*   deg     = (int*)alloc((size_t)N);
    int*   off     = (int*)alloc((size_t)N + 1);
    int*   cursor  = (int*)alloc((size_t)N);
    int*   csr_j   = (int*)alloc((size_t)Ed);
    float* csr_env = alloc((size_t)Ed);
    float* csr_unit= alloc((size_t)Ed * 3);
    float* csr_rbfe= alloc((size_t)Ed * NRBF);
    float* h       = alloc((size_t)SP);
    float* cat     = alloc((size_t)N * 256);
    float* phi     = alloc((size_t)N * 384);   // reused for 'a'
    float* vA      = alloc((size_t)3 * SP);
    float* vB      = alloc((size_t)3 * SP);
    float* v_v     = alloc((size_t)3 * SP);
    (void)ws_size; (void)n_in; (void)out_size;

    // init s <- cg_s, vA <- 0
    {
        int n = 3 * SP;
        init_s_kernel<<<(n + 255) / 256, 256, 0, stream>>>(cg_s, s, vA, SP, n);
    }

    // CSR build (once per launch)
    hipMemsetAsync(deg, 0, (size_t)N * sizeof(int), stream);
    hist_kernel<<<(Ed + 255) / 256, 256, 0, stream>>>(nbr, deg, Ed);
    scan_kernel<<<1, 1024, 0, stream>>>(deg, off, cursor, N);
    scatter_geom_kernel<<<(Ed + 255) / 256, 256, 0, stream>>>(
        nbr, xyz, cursor, csr_j, csr_env, csr_unit, csr_rbfe, Ed);

    float* vold = vA;
    float* vnew = vB;
    dim3 g1((N + BM - 1) / BM, FEAT / BN);
    dim3 g2((N + BM - 1) / BM, (3 * FEAT) / BN);
    const int aggr_blocks = 2560;

    for (int l = 0; l < NCONV; ++l) {
        const float* W1  = msg_W1  + (long)l * FEAT * FEAT;
        const float* b1  = msg_b1  + (long)l * FEAT;
        const float* W2  = msg_W2  + (long)l * 3 * FEAT * FEAT;
        const float* b2  = msg_b2  + (long)l * 3 * FEAT;
        const float* dW  = dist_W  + (long)l * 3 * FEAT * NRBF;
        const float* db  = dist_b  + (long)l * 3 * FEAT;
        const float* U   = upd_U   + (long)l * FEAT * FEAT;
        const float* V   = upd_V   + (long)l * FEAT * FEAT;
        const float* sW1 = upd_sW1 + (long)l * FEAT * 2 * FEAT;
        const float* sb1 = upd_sb1 + (long)l * FEAT;
        const float* sW2 = upd_sW2 + (long)l * 3 * FEAT * FEAT;
        const float* sb2 = upd_sb2 + (long)l * 3 * FEAT;

        // phi-MLP
        gemm_bias_kernel<<<g1, 256, 0, stream>>>(s, W1, b1, h, N, FEAT, FEAT, 1);
        gemm_bias_kernel<<<g2, 256, 0, stream>>>(h, W2, b2, phi, N, 3 * FEAT, FEAT, 0);

        // atomic-free message aggregation: s += sum, vnew = vold + sum
        edge_aggr_kernel<<<aggr_blocks, 128, 0, stream>>>(
            off, csr_j, csr_env, csr_unit, csr_rbfe, phi, vold, dW, db,
            s, vnew, N, SP);

        // u_v / v_v per plane
        for (int d = 0; d < 3; ++d) {
            gemm_bias_kernel<<<g1, 256, 0, stream>>>(
                vnew + (long)d * SP, U, nullptr, u_v + (long)d * SP, N, FEAT, FEAT, 0);
            gemm_bias_kernel<<<g1, 256, 0, stream>>>(
                vnew + (long)d * SP, V, nullptr, v_v + (long)d * SP, N, FEAT, FEAT, 0);
        }

        // gate MLP
        cat_norm_kernel<<<(SP + 255) / 256, 256, 0, stream>>>(s, v_v, cat, SP);
        gemm_bias_kernel<<<g1, 256, 0, stream>>>(cat, sW1, sb1, h, N, FEAT, 2 * FEAT, 1);
        gemm_bias_kernel<<<g2, 256, 0, stream>>>(h, sW2, sb2, phi, N, 3 * FEAT, FEAT, 0);

        // final update ('phi' now holds 'a')
        update_sv_kernel<<<(SP + 255) / 256, 256, 0, stream>>>(s, vnew, u_v, v_v, phi, SP);

        float* tmp = vold; vold = vnew; vnew = tmp;
    }

    write_out_kernel<<<(SP + 255) / 256, 256, 0, stream>>>(vold, outv, SP);
}

// Round 5
// 1066.870 us; speedup vs baseline: 2.1986x; 1.5812x over previous
//
#include <hip/hip_runtime.h>
#include <math.h>

#define FEAT 128
#define NRBF 20
#define NCONV 3
#define PI_F 3.14159265358979323846f

typedef __attribute__((ext_vector_type(8))) short short8;
typedef __attribute__((ext_vector_type(4))) float floatx4;

__device__ inline float b2f(unsigned short u) {
    union { unsigned int i; float f; } c; c.i = ((unsigned int)u) << 16; return c.f;
}
__device__ inline unsigned short f2b(float x) {
    union { float f; unsigned int i; } c; c.f = x;
    unsigned int u = c.i;
    return (unsigned short)((u + 0x7fffu + ((u >> 16) & 1u)) >> 16);
}

// ---------------------------------------------------------------------------
// Split-precision MFMA GEMM: C[M,N] = A[M,K] @ W[N,K]^T (+bias)(opt silu).
// A fp32 (split to bf16 hi/lo at staging), W pre-split bf16 hi/lo.
// acc += Ah*Wh + Ah*Wl + Al*Wh  (~fp16-accurate, lo*lo dropped).
// 128x128 tile, BK=32, 256 thr = 4 waves, per-wave 64x64 via 4x4 16x16x32.
// N%128==0, K%32==0. M-tail clamped. Output fp32.
// ---------------------------------------------------------------------------
__global__ __launch_bounds__(256) void gemm_split_kernel(
    const float* __restrict__ A,
    const unsigned short* __restrict__ Whi, const unsigned short* __restrict__ Wlo,
    const float* __restrict__ bias, float* __restrict__ C,
    int M, int N, int K, int act)
{
    __shared__ __align__(16) unsigned short Ah[128 * 40];
    __shared__ __align__(16) unsigned short Al[128 * 40];
    __shared__ __align__(16) unsigned short Wh[128 * 40];
    __shared__ __align__(16) unsigned short Wl[128 * 40];
    const int t    = threadIdx.x;
    const int m0   = blockIdx.x * 128;
    const int n0   = blockIdx.y * 128;
    const int wv   = t >> 6;
    const int lane = t & 63;
    const int wm   = (wv >> 1) * 64;
    const int wn   = (wv & 1) * 64;
    const int lr   = lane & 15;
    const int lk   = (lane >> 4) * 8;
    const int arow = t >> 3;          // 32 rows/pass, 4 passes
    const int acol = (t & 7) * 4;
    const int wrow = t >> 2;          // 64 rows/pass, 2 passes
    const int wcol = (t & 3) * 8;

    floatx4 acc[4][4] = {};

    for (int k0 = 0; k0 < K; k0 += 32) {
        #pragma unroll
        for (int h = 0; h < 4; ++h) {
            int r = arow + h * 32;
            int m = m0 + r; if (m >= M) m = M - 1;   // clamp tail
            float4 av = *(const float4*)(A + (long)m * K + k0 + acol);
            float xs[4] = {av.x, av.y, av.z, av.w};
            unsigned short hh[4], ll[4];
            #pragma unroll
            for (int q = 0; q < 4; ++q) {
                hh[q] = f2b(xs[q]);
                ll[q] = f2b(xs[q] - b2f(hh[q]));
            }
            *(ushort4*)(&Ah[r * 40 + acol]) = make_ushort4(hh[0], hh[1], hh[2], hh[3]);
            *(ushort4*)(&Al[r * 40 + acol]) = make_ushort4(ll[0], ll[1], ll[2], ll[3]);
        }
        #pragma unroll
        for (int h = 0; h < 2; ++h) {
            int r = wrow + h * 64;
            *(uint4*)(&Wh[r * 40 + wcol]) =
                *(const uint4*)(Whi + (long)(n0 + r) * K + k0 + wcol);
            *(uint4*)(&Wl[r * 40 + wcol]) =
                *(const uint4*)(Wlo + (long)(n0 + r) * K + k0 + wcol);
        }
        __syncthreads();
        short8 ah[4], al[4], wh[4], wl[4];
        #pragma unroll
        for (int i = 0; i < 4; ++i) {
            ah[i] = *(const short8*)(&Ah[(wm + i * 16 + lr) * 40 + lk]);
            al[i] = *(const short8*)(&Al[(wm + i * 16 + lr) * 40 + lk]);
            wh[i] = *(const short8*)(&Wh[(wn + i * 16 + lr) * 40 + lk]);
            wl[i] = *(const short8*)(&Wl[(wn + i * 16 + lr) * 40 + lk]);
        }
        #pragma unroll
        for (int i = 0; i < 4; ++i)
            #pragma unroll
            for (int j = 0; j < 4; ++j) {
                acc[i][j] = __builtin_amdgcn_mfma_f32_16x16x32_bf16(
                    ah[i], wh[j], acc[i][j], 0, 0, 0);
                acc[i][j] = __builtin_amdgcn_mfma_f32_16x16x32_bf16(
                    ah[i], wl[j], acc[i][j], 0, 0, 0);
                acc[i][j] = __builtin_amdgcn_mfma_f32_16x16x32_bf16(
                    al[i], wh[j], acc[i][j], 0, 0, 0);
            }
        __syncthreads();
    }

    // epilogue: C/D layout col=lane&15, row=(lane>>4)*4+reg  [m89]
    #pragma unroll
    for (int i = 0; i < 4; ++i) {
        #pragma unroll
        for (int r = 0; r < 4; ++r) {
            int m = m0 + wm + i * 16 + (lane >> 4) * 4 + r;
            if (m >= M) continue;
            #pragma unroll
            for (int j = 0; j < 4; ++j) {
                int n = n0 + wn + j * 16 + (lane & 15);
                float x = acc[i][j][r];
                if (bias) x += bias[n];
                if (act) x *= 1.f / (1.f + __expf(-x));
                C[(long)m * N + n] = x;
            }
        }
    }
}

// ---------------------------------------------------------------------------
// fp32 -> bf16 hi/lo split (weights, once per launch)
// ---------------------------------------------------------------------------
__global__ __launch_bounds__(256) void split_kernel(
    const float* __restrict__ src, unsigned short* __restrict__ hi,
    unsigned short* __restrict__ lo, int n)
{
    int i = blockIdx.x * blockDim.x + threadIdx.x;
    if (i >= n) return;
    float x = src[i];
    unsigned short h = f2b(x);
    hi[i] = h;
    lo[i] = f2b(x - b2f(h));
}

// ---------------------------------------------------------------------------
// CSR build (unchanged from R1)
// ---------------------------------------------------------------------------
__global__ __launch_bounds__(256) void hist_kernel(
    const int* __restrict__ nbr, int* __restrict__ deg, int Ed)
{
    int e = blockIdx.x * blockDim.x + threadIdx.x;
    if (e >= Ed) return;
    int E = Ed >> 1;
    int i = (e < E) ? nbr[2 * e] : nbr[2 * (e - E) + 1];
    atomicAdd(&deg[i], 1);
}

__device__ inline int wave_incl_scan(int x, int lane)
{
    #pragma unroll
    for (int s = 1; s < 64; s <<= 1) {
        int y = __shfl_up(x, s, 64);
        if (lane >= s) x += y;
    }
    return x;
}

__global__ __launch_bounds__(1024) void scan_kernel(
    const int* __restrict__ deg, int* __restrict__ off,
    int* __restrict__ cursor, int N)
{
    __shared__ int wsum[16];
    __shared__ int carry_s;
    const int t = threadIdx.x;
    const int lane = t & 63;
    const int w = t >> 6;
    if (t == 0) { carry_s = 0; off[0] = 0; }
    __syncthreads();
    for (int base = 0; base < N; base += 1024) {
        int i = base + t;
        int x = (i < N) ? deg[i] : 0;
        int sc = wave_incl_scan(x, lane);
        if (lane == 63) wsum[w] = sc;
        __syncthreads();
        if (w == 0) {
            int v = (lane < 16) ? wsum[lane] : 0;
            int vs = wave_incl_scan(v, lane);
            if (lane < 16) wsum[lane] = vs;
        }
        __syncthreads();
        int waveoff = (w > 0) ? wsum[w - 1] : 0;
        int inc = sc + waveoff + carry_s;
        if (i < N) { off[i + 1] = inc; cursor[i] = inc - x; }
        __syncthreads();
        if (t == 1023) carry_s = inc;
        __syncthreads();
    }
}

__global__ __launch_bounds__(256) void scatter_geom_kernel(
    const int* __restrict__ nbr, const float* __restrict__ xyz,
    int* __restrict__ cursor, int* __restrict__ csr_j,
    float* __restrict__ csr_env, float* __restrict__ csr_unit,
    float* __restrict__ csr_rbfe, int Ed)
{
    int e = blockIdx.x * blockDim.x + threadIdx.x;
    if (e >= Ed) return;
    int E = Ed >> 1;
    int i, j;
    if (e < E) { i = nbr[2 * e];         j = nbr[2 * e + 1]; }
    else       { int u = e - E; i = nbr[2 * u + 1]; j = nbr[2 * u]; }

    int p = atomicAdd(&cursor[i], 1);
    csr_j[p] = j;

    float rx = xyz[3 * j + 0] - xyz[3 * i + 0];
    float ry = xyz[3 * j + 1] - xyz[3 * i + 1];
    float rz = xyz[3 * j + 2] - xyz[3 * i + 2];
    float d   = sqrtf(rx * rx + ry * ry + rz * rz);
    float inv = 1.f / d;
    csr_unit[3 * p + 0] = rx * inv;
    csr_unit[3 * p + 1] = ry * inv;
    csr_unit[3 * p + 2] = rz * inv;
    float ev = (d < 20.f) ? 0.5f * (__cosf(PI_F * d / 20.f) + 1.f) : 0.f;
    csr_env[p] = ev;
    float base = PI_F * d / 20.f;
    #pragma unroll
    for (int k = 0; k < NRBF; ++k)
        csr_rbfe[(long)p * NRBF + k] = ev * __sinf((float)(k + 1) * base) * inv;
}

// ---------------------------------------------------------------------------
// Edge aggregation, atomic-free, fp32 gathers (proven accurate in R1).
// ---------------------------------------------------------------------------
__global__ __launch_bounds__(128) void edge_aggr_kernel(
    const int* __restrict__ off, const int* __restrict__ csr_j,
    const float* __restrict__ csr_env, const float* __restrict__ csr_unit,
    const float* __restrict__ csr_rbfe,
    const float* __restrict__ phi, const float* __restrict__ vold,
    const float* __restrict__ distW, const float* __restrict__ distb,
    float* __restrict__ s, float* __restrict__ vnew, int N, int SP)
{
    const int f = threadIdx.x;
    float w0c[NRBF], w1c[NRBF], w2c[NRBF];
    const float b0 = distb[f];
    const float b1 = distb[128 + f];
    const float b2 = distb[256 + f];
    #pragma unroll
    for (int k = 0; k < NRBF; ++k) {
        w0c[k] = distW[(long)f * NRBF + k];
        w1c[k] = distW[(long)(128 + f) * NRBF + k];
        w2c[k] = distW[(long)(256 + f) * NRBF + k];
    }

    for (int node = blockIdx.x; node < N; node += gridDim.x) {
        const int p0 = off[node], p1 = off[node + 1];
        float ssum = 0.f, v0 = 0.f, v1 = 0.f, v2 = 0.f;
        for (int p = p0; p < p1; ++p) {
            int j = csr_j[p];
            float ev = csr_env[p];
            float ux = csr_unit[3 * p + 0];
            float uy = csr_unit[3 * p + 1];
            float uz = csr_unit[3 * p + 2];
            const float* rb = csr_rbfe + (long)p * NRBF;
            float w0 = ev * b0, w1 = ev * b1, w2 = ev * b2;
            #pragma unroll
            for (int k = 0; k < NRBF; ++k) {
                float r = rb[k];
                w0 += r * w0c[k];
                w1 += r * w1c[k];
                w2 += r * w2c[k];
            }
            long jb = (long)j * 384;
            float i0 = phi[jb + f]       * w0;
            float i1 = phi[jb + 128 + f] * w1;
            float i2 = phi[jb + 256 + f] * w2;
            long jv = (long)j * FEAT + f;
            ssum += i1;
            v0 += i2 * ux + i0 * vold[jv];
            v1 += i2 * uy + i0 * vold[SP + jv];
            v2 += i2 * uz + i0 * vold[2 * SP + jv];
        }
        long iv = (long)node * FEAT + f;
        s[iv] += ssum;
        vnew[iv]          = vold[iv]          + v0;
        vnew[SP + iv]     = vold[SP + iv]     + v1;
        vnew[2 * SP + iv] = vold[2 * SP + iv] + v2;
    }
}

// ---------------------------------------------------------------------------
// Elementwise kernels
// ---------------------------------------------------------------------------
__global__ __launch_bounds__(256) void init_s_kernel(
    const float* __restrict__ cg_s, float* __restrict__ s,
    float* __restrict__ vA, int nS, int nV)
{
    int idx = blockIdx.x * blockDim.x + threadIdx.x;
    if (idx < nS) s[idx] = cg_s[idx];
    if (idx < nV) vA[idx] = 0.f;
}

__global__ __launch_bounds__(256) void cat_norm_kernel(
    const float* __restrict__ s, const float* __restrict__ vv,
    float* __restrict__ cat, int SP)
{
    int idx = blockIdx.x * blockDim.x + threadIdx.x;
    if (idx >= SP) return;
    int n = idx >> 7, g = idx & 127;
    float a0 = vv[idx], a1 = vv[SP + idx], a2 = vv[2 * SP + idx];
    cat[(long)n * 256 + g]       = s[idx];
    cat[(long)n * 256 + 128 + g] = sqrtf(a0 * a0 + a1 * a1 + a2 * a2);
}

__global__ __launch_bounds__(256) void update_sv_kernel(
    float* __restrict__ s, float* __restrict__ v,
    const float* __restrict__ uv, const float* __restrict__ vv,
    const float* __restrict__ a, int SP)
{
    int idx = blockIdx.x * blockDim.x + threadIdx.x;
    if (idx >= SP) return;
    int n = idx >> 7, g = idx & 127;
    float u0 = uv[idx], u1 = uv[SP + idx], u2 = uv[2 * SP + idx];
    float w0 = vv[idx], w1 = vv[SP + idx], w2 = vv[2 * SP + idx];
    long ab = (long)n * 384;
    float dot = u0 * w0 + u1 * w1 + u2 * w2;
    s[idx] += dot * a[ab + 128 + g] + a[ab + 256 + g];
    float g0 = a[ab + g];
    v[idx]          += u0 * g0;
    v[SP + idx]     += u1 * g0;
    v[2 * SP + idx] += u2 * g0;
}

__global__ __launch_bounds__(256) void write_out_kernel(
    const float* __restrict__ vfin, float* __restrict__ outv, int SP)
{
    int idx = blockIdx.x * blockDim.x + threadIdx.x;
    if (idx >= SP) return;
    outv[(long)idx * 3 + 0] = vfin[idx];
    outv[(long)idx * 3 + 1] = vfin[SP + idx];
    outv[(long)idx * 3 + 2] = vfin[2 * SP + idx];
}

// ---------------------------------------------------------------------------
extern "C" void kernel_launch(void* const* d_in, const int* in_sizes, int n_in,
                              void* d_out, int out_size, void* d_ws, size_t ws_size,
                              hipStream_t stream)
{
    const float* xyz     = (const float*)d_in[0];
    const int*   nbr     = (const int*)  d_in[1];
    const float* cg_s    = (const float*)d_in[2];
    const float* msg_W1  = (const float*)d_in[3];
    const float* msg_b1  = (const float*)d_in[4];
    const float* msg_W2  = (const float*)d_in[5];
    const float* msg_b2  = (const float*)d_in[6];
    const float* dist_W  = (const float*)d_in[7];
    const float* dist_b  = (const float*)d_in[8];
    const float* upd_U   = (const float*)d_in[9];
    const float* upd_V   = (const float*)d_in[10];
    const float* upd_sW1 = (const float*)d_in[11];
    const float* upd_sb1 = (const float*)d_in[12];
    const float* upd_sW2 = (const float*)d_in[13];
    const float* upd_sb2 = (const float*)d_in[14];

    const int E  = in_sizes[1] / 2;
    const int Ed = 2 * E;
    const int N  = in_sizes[2] / FEAT;
    const int SP = N * FEAT;

    float* s    = (float*)d_out;
    float* outv = (float*)d_out + (long)SP;
    float* u_v  = outv;   // alias: u_v planes dead by output time

    // workspace carve-up (fp32-element units, 256-elem aligned)
    float* w = (float*)d_ws;
    size_t off_ = 0;
    auto alloc = [&](size_t nelem) {
        float* p = w + off_;
        off_ += (nelem + 255) & ~(size_t)255;
        return p;
    };
    auto allocb = [&](size_t nelem) {   // bf16 elements
        return (unsigned short*)alloc((nelem + 1) / 2);
    };
    int*   deg      = (int*)alloc((size_t)N);
    int*   off      = (int*)alloc((size_t)N + 1);
    int*   cursor   = (int*)alloc((size_t)N);
    int*   csr_j    = (int*)alloc((size_t)Ed);
    float* csr_env  = alloc((size_t)Ed);
    float* csr_unit = alloc((size_t)Ed * 3);
    float* csr_rbfe = alloc((size_t)Ed * NRBF);
    float* h        = alloc((size_t)SP);
    float* cat      = alloc((size_t)N * 256);
    float* phi      = alloc((size_t)N * 384);   // reused for 'a'
    float* v_v      = alloc((size_t)3 * SP);
    float* vA       = alloc((size_t)3 * SP);
    float* vB       = alloc((size_t)3 * SP);
    const int n1 = NCONV * FEAT * FEAT;
    const int n2 = NCONV * 3 * FEAT * FEAT;
    const int n3 = NCONV * FEAT * 2 * FEAT;
    unsigned short* w1h  = allocb((size_t)n1);
    unsigned short* w1l  = allocb((size_t)n1);
    unsigned short* w2h  = allocb((size_t)n2);
    unsigned short* w2l  = allocb((size_t)n2);
    unsigned short* uh   = allocb((size_t)n1);
    unsigned short* ul   = allocb((size_t)n1);
    unsigned short* vh   = allocb((size_t)n1);
    unsigned short* vl   = allocb((size_t)n1);
    unsigned short* sw1h = allocb((size_t)n3);
    unsigned short* sw1l = allocb((size_t)n3);
    unsigned short* sw2h = allocb((size_t)n2);
    unsigned short* sw2l = allocb((size_t)n2);
    (void)ws_size; (void)n_in; (void)out_size;

    // weight split (once per launch)
    split_kernel<<<(n1 + 255) / 256, 256, 0, stream>>>(msg_W1, w1h, w1l, n1);
    split_kernel<<<(n2 + 255) / 256, 256, 0, stream>>>(msg_W2, w2h, w2l, n2);
    split_kernel<<<(n1 + 255) / 256, 256, 0, stream>>>(upd_U, uh, ul, n1);
    split_kernel<<<(n1 + 255) / 256, 256, 0, stream>>>(upd_V, vh, vl, n1);
    split_kernel<<<(n3 + 255) / 256, 256, 0, stream>>>(upd_sW1, sw1h, sw1l, n3);
    split_kernel<<<(n2 + 255) / 256, 256, 0, stream>>>(upd_sW2, sw2h, sw2l, n2);

    // init s <- cg_s, vA <- 0
    {
        int n = 3 * SP;
        init_s_kernel<<<(n + 255) / 256, 256, 0, stream>>>(cg_s, s, vA, SP, n);
    }

    // CSR build (once per launch)
    hipMemsetAsync(deg, 0, (size_t)N * sizeof(int), stream);
    hist_kernel<<<(Ed + 255) / 256, 256, 0, stream>>>(nbr, deg, Ed);
    scan_kernel<<<1, 1024, 0, stream>>>(deg, off, cursor, N);
    scatter_geom_kernel<<<(Ed + 255) / 256, 256, 0, stream>>>(
        nbr, xyz, cursor, csr_j, csr_env, csr_unit, csr_rbfe, Ed);

    float* vold = vA;
    float* vnew = vB;
    dim3 gN128((N + 127) / 128, 1);
    dim3 gN384((N + 127) / 128, 3);
    dim3 g3N128((3 * N + 127) / 128, 1);
    const int aggr_blocks = 2560;

    for (int l = 0; l < NCONV; ++l) {
        const float* b1  = msg_b1  + (long)l * FEAT;
        const float* b2  = msg_b2  + (long)l * 3 * FEAT;
        const float* dW  = dist_W  + (long)l * 3 * FEAT * NRBF;
        const float* db  = dist_b  + (long)l * 3 * FEAT;
        const float* sb1 = upd_sb1 + (long)l * FEAT;
        const float* sb2 = upd_sb2 + (long)l * 3 * FEAT;
        const long o1 = (long)l * FEAT * FEAT;
        const long o2 = (long)l * 3 * FEAT * FEAT;
        const long o3 = (long)l * FEAT * 2 * FEAT;

        // phi-MLP (split-precision MFMA)
        gemm_split_kernel<<<gN128, 256, 0, stream>>>(
            s, w1h + o1, w1l + o1, b1, h, N, FEAT, FEAT, 1);
        gemm_split_kernel<<<gN384, 256, 0, stream>>>(
            h, w2h + o2, w2l + o2, b2, phi, N, 3 * FEAT, FEAT, 0);

        // atomic-free message aggregation (fp32)
        edge_aggr_kernel<<<aggr_blocks, 128, 0, stream>>>(
            off, csr_j, csr_env, csr_unit, csr_rbfe, phi, vold,
            dW, db, s, vnew, N, SP);

        // u_v / v_v: batched over 3 planes (M = 3N)
        gemm_split_kernel<<<g3N128, 256, 0, stream>>>(
            vnew, uh + o1, ul + o1, nullptr, u_v, 3 * N, FEAT, FEAT, 0);
        gemm_split_kernel<<<g3N128, 256, 0, stream>>>(
            vnew, vh + o1, vl + o1, nullptr, v_v, 3 * N, FEAT, FEAT, 0);

        // gate MLP
        cat_norm_kernel<<<(SP + 255) / 256, 256, 0, stream>>>(s, v_v, cat, SP);
        gemm_split_kernel<<<gN128, 256, 0, stream>>>(
            cat, sw1h + o3, sw1l + o3, sb1, h, N, FEAT, 2 * FEAT, 1);
        gemm_split_kernel<<<gN384, 256, 0, stream>>>(
            h, sw2h + o2, sw2l + o2, sb2, phi, N, 3 * FEAT, FEAT, 0);

        // final update ('phi' now holds 'a')
        update_sv_kernel<<<(SP + 255) / 256, 256, 0, stream>>>(
            s, vnew, u_v, v_v, phi, SP);

        float* tmp = vold; vold = vnew; vnew = tmp;
    }

    write_out_kernel<<<(SP + 255) / 256, 256, 0, stream>>>(vold, outv, SP);
}